// Round 3
// baseline (264.577 us; speedup 1.0000x reference)
//
#include <hip/hip_runtime.h>

// Bilinear sampling: x is (B=128, H=224, W=224, 5) f32 interleaved
// [r,g,b,X,Y]; out is (B,224,224,3) f32.
//
// R5: R4b ran at VGPR=44 -> compiler serialized the 16-gather batch to
// chase occupancy; MLP theory never materialized. This round forces it:
//  - __launch_bounds__(256, 4): VGPR cap 128 (occupancy was 50% = 16
//    waves/CU anyway, so 4 waves/SIMD costs nothing measured).
//  - sched_barrier(0) between gather-issue and combine: no load sinks
//    past the fence -> all 16 gathers in flight per wave.
// Everything else unchanged: 4 consecutive pixels/thread (5 coalesced
// dwordx4 input loads), paired-float4 corner trick (2 contiguous 16B
// loads per sample row), XCD swizzle, NT output stores.
// Inputs guarantee X,Y in [0,223) so the reference's pad/clip never fires.

#define HH 224
#define WW 224
#define NB 128

constexpr int PIX_PER_IMG    = HH * WW;                      // 50176
constexpr int BLOCK          = 256;
constexpr int P              = 4;                            // consecutive pixels/thread
constexpr int PIX_PER_BLOCK  = BLOCK * P;                    // 1024
constexpr int BLOCKS_PER_IMG = PIX_PER_IMG / PIX_PER_BLOCK;  // 49 (exact)
constexpr int TOTAL_BLOCKS   = NB * BLOCKS_PER_IMG;          // 6272
constexpr int ROW_BYTES      = WW * 5 * 4;                   // 4480

typedef float f32x4 __attribute__((ext_vector_type(4)));

__device__ __forceinline__ float4 ld4(const float* p) {
    return *reinterpret_cast<const float4*>(p);
}

__global__ __launch_bounds__(BLOCK, 4) void bilinear_kernel(
    const float* __restrict__ x, float* __restrict__ out)
{
    // XCD-aware swizzle: all blocks of image b land on XCD (b & 7).
    int i    = blockIdx.x;
    int xcd  = i & 7;
    int slot = i >> 3;
    int b    = xcd + 8 * (slot / BLOCKS_PER_IMG);
    int tile = slot % BLOCKS_PER_IMG;
    int pix0 = tile * PIX_PER_BLOCK + (int)threadIdx.x * P;

    const float* img = x + (size_t)b * (PIX_PER_IMG * 5);
    const float* xp  = img + (size_t)pix0 * 5;

    // This thread's 4 pixels = 20 contiguous floats [r,g,b,X,Y]x4,
    // 80B-aligned -> 5 coalesced dwordx4 loads.
    float4 v0 = ld4(xp +  0);
    float4 v1 = ld4(xp +  4);
    float4 v2 = ld4(xp +  8);
    float4 v3 = ld4(xp + 12);
    float4 v4 = ld4(xp + 16);

    // pixel k: X at float 5k+3, Y at float 5k+4
    float Xs[P] = { v0.w, v2.x, v3.y, v4.z };
    float Ys[P] = { v1.x, v2.y, v3.z, v4.w };

    float4 a0[P], b0[P], a1[P], b1[P];
    float  wx[P], wy[P];
    const char* base = reinterpret_cast<const char*>(img);

    // Issue all 16 gathers before any combine -> max memory-level parallelism.
#pragma unroll
    for (int k = 0; k < P; ++k) {
        float fx = floorf(Xs[k]);
        float fy = floorf(Ys[k]);
        wx[k] = Xs[k] - fx;
        wy[k] = Ys[k] - fy;
        // byte offset = (fyi*224 + fxi)*20; exact in fp32 (all ints < 2^24)
        int voff = (int)fmaf(fy, (float)ROW_BYTES, fx * 20.0f);
        const char* q0 = base + voff;                    // row fyi, col fxi
        a0[k] = ld4(reinterpret_cast<const float*>(q0));          // r,g,b,(X)
        b0[k] = ld4(reinterpret_cast<const float*>(q0 + 16));     // (Y),r',g',b'
        a1[k] = ld4(reinterpret_cast<const float*>(q0 + ROW_BYTES));
        b1[k] = ld4(reinterpret_cast<const float*>(q0 + ROW_BYTES + 16));
    }

    // Fence: no gather may be sunk past this point; all 16 are in flight.
    __builtin_amdgcn_sched_barrier(0);

    float o[3 * P];
#pragma unroll
    for (int k = 0; k < P; ++k) {
        float w_tl = (1.f - wx[k]) * (1.f - wy[k]);
        float w_tr = wx[k] * (1.f - wy[k]);
        float w_bl = (1.f - wx[k]) * wy[k];
        float w_br = wx[k] * wy[k];
        o[3*k+0] = w_tl*a0[k].x + w_tr*b0[k].y + w_bl*a1[k].x + w_br*b1[k].y;
        o[3*k+1] = w_tl*a0[k].y + w_tr*b0[k].z + w_bl*a1[k].y + w_br*b1[k].z;
        o[3*k+2] = w_tl*a0[k].z + w_tr*b0[k].w + w_bl*a1[k].z + w_br*b1[k].w;
    }

    // 4 pixels * 12B = 48B contiguous, 48B-aligned -> 3 NT dwordx4 stores.
    float* op = out + ((size_t)b * PIX_PER_IMG + pix0) * 3;
    f32x4* ov = reinterpret_cast<f32x4*>(op);
    f32x4 s0 = { o[0], o[1], o[2],  o[3]  };
    f32x4 s1 = { o[4], o[5], o[6],  o[7]  };
    f32x4 s2 = { o[8], o[9], o[10], o[11] };
    __builtin_nontemporal_store(s0, ov + 0);
    __builtin_nontemporal_store(s1, ov + 1);
    __builtin_nontemporal_store(s2, ov + 2);
}

extern "C" void kernel_launch(void* const* d_in, const int* in_sizes, int n_in,
                              void* d_out, int out_size, void* d_ws, size_t ws_size,
                              hipStream_t stream) {
    const float* x = (const float*)d_in[0];
    float* out = (float*)d_out;
    bilinear_kernel<<<TOTAL_BLOCKS, BLOCK, 0, stream>>>(x, out);
}

// Round 4
// 253.888 us; speedup vs baseline: 1.0421x; 1.0421x over previous
//
#include <hip/hip_runtime.h>

// Bilinear sampling: x is (B=128, H=224, W=224, 5) f32 interleaved
// [r,g,b,X,Y]; out is (B,224,224,3) f32.
//
// R6: engage the MLP lever FOR REAL. R4b/R5 ran at VGPR=40-44 -> the
// compiler never kept the 16 gathers in flight (arrays + pragma unroll
// got re-rolled / pipelined). This version:
//  - computes all 4 sample addresses + weights first (named scalars),
//  - issues 16 NAMED float4 loads back-to-back (no arrays, no loop),
//  - sched_barrier(0) so no load sinks past the fence,
//  - then combines (consumer waits are partial vmcnt drains, in order).
// Reverted R5's __launch_bounds__(256,4) (it regressed 118->130us).
// Kept: 4 consecutive pixels/thread (5 coalesced dwordx4 input loads),
// paired-float4 corner trick, XCD swizzle, NT output stores.
// Inputs guarantee X,Y in [0,223) so the reference's pad/clip never fires.

#define HH 224
#define WW 224
#define NB 128

constexpr int PIX_PER_IMG    = HH * WW;                      // 50176
constexpr int BLOCK          = 256;
constexpr int P              = 4;                            // consecutive pixels/thread
constexpr int PIX_PER_BLOCK  = BLOCK * P;                    // 1024
constexpr int BLOCKS_PER_IMG = PIX_PER_IMG / PIX_PER_BLOCK;  // 49 (exact)
constexpr int TOTAL_BLOCKS   = NB * BLOCKS_PER_IMG;          // 6272
constexpr int ROW_BYTES      = WW * 5 * 4;                   // 4480

typedef float f32x4 __attribute__((ext_vector_type(4)));

__device__ __forceinline__ float4 ld4(const float* p) {
    return *reinterpret_cast<const float4*>(p);
}

__global__ __launch_bounds__(BLOCK) void bilinear_kernel(
    const float* __restrict__ x, float* __restrict__ out)
{
    // XCD-aware swizzle: all blocks of image b land on XCD (b & 7).
    int i    = blockIdx.x;
    int xcd  = i & 7;
    int slot = i >> 3;
    int b    = xcd + 8 * (slot / BLOCKS_PER_IMG);
    int tile = slot % BLOCKS_PER_IMG;
    int pix0 = tile * PIX_PER_BLOCK + (int)threadIdx.x * P;

    const float* img = x + (size_t)b * (PIX_PER_IMG * 5);
    const float* xp  = img + (size_t)pix0 * 5;

    // This thread's 4 pixels = 20 contiguous floats [r,g,b,X,Y]x4,
    // 80B-aligned -> 5 coalesced dwordx4 loads.
    float4 v0 = ld4(xp +  0);
    float4 v1 = ld4(xp +  4);
    float4 v2 = ld4(xp +  8);
    float4 v3 = ld4(xp + 12);
    float4 v4 = ld4(xp + 16);

    // pixel k: X at float 5k+3, Y at float 5k+4
    float X0 = v0.w, X1 = v2.x, X2 = v3.y, X3 = v4.z;
    float Y0 = v1.x, Y1 = v2.y, Y2 = v3.z, Y3 = v4.w;

    const char* base = reinterpret_cast<const char*>(img);

    // --- addresses + weights, all before any gather ---
#define PREP(k)                                                              \
    float fx##k = floorf(X##k);                                              \
    float fy##k = floorf(Y##k);                                              \
    float wx##k = X##k - fx##k;                                              \
    float wy##k = Y##k - fy##k;                                              \
    /* byte offset = (fyi*224 + fxi)*20; exact in fp32 (ints < 2^24) */      \
    const char* q##k = base + (int)fmaf(fy##k, (float)ROW_BYTES, fx##k * 20.0f);

    PREP(0) PREP(1) PREP(2) PREP(3)

    // --- 16 gathers, named results, issued back-to-back ---
#define GATHER(k)                                                            \
    float4 a0_##k = ld4(reinterpret_cast<const float*>(q##k));               \
    float4 b0_##k = ld4(reinterpret_cast<const float*>(q##k + 16));          \
    float4 a1_##k = ld4(reinterpret_cast<const float*>(q##k + ROW_BYTES));   \
    float4 b1_##k = ld4(reinterpret_cast<const float*>(q##k + ROW_BYTES + 16));

    GATHER(0) GATHER(1) GATHER(2) GATHER(3)

    // Fence: no gather may be sunk past this point; all 16 are in flight.
    __builtin_amdgcn_sched_barrier(0);

    float o[3 * P];
#define COMBINE(k)                                                           \
    {                                                                        \
        float w_tl = (1.f - wx##k) * (1.f - wy##k);                          \
        float w_tr = wx##k * (1.f - wy##k);                                  \
        float w_bl = (1.f - wx##k) * wy##k;                                  \
        float w_br = wx##k * wy##k;                                          \
        o[3*k+0] = w_tl*a0_##k.x + w_tr*b0_##k.y + w_bl*a1_##k.x + w_br*b1_##k.y; \
        o[3*k+1] = w_tl*a0_##k.y + w_tr*b0_##k.z + w_bl*a1_##k.y + w_br*b1_##k.z; \
        o[3*k+2] = w_tl*a0_##k.z + w_tr*b0_##k.w + w_bl*a1_##k.z + w_br*b1_##k.w; \
    }

    COMBINE(0) COMBINE(1) COMBINE(2) COMBINE(3)

    // 4 pixels * 12B = 48B contiguous, 48B-aligned -> 3 NT dwordx4 stores.
    float* op = out + ((size_t)b * PIX_PER_IMG + pix0) * 3;
    f32x4* ov = reinterpret_cast<f32x4*>(op);
    f32x4 s0 = { o[0], o[1], o[2],  o[3]  };
    f32x4 s1 = { o[4], o[5], o[6],  o[7]  };
    f32x4 s2 = { o[8], o[9], o[10], o[11] };
    __builtin_nontemporal_store(s0, ov + 0);
    __builtin_nontemporal_store(s1, ov + 1);
    __builtin_nontemporal_store(s2, ov + 2);
}

extern "C" void kernel_launch(void* const* d_in, const int* in_sizes, int n_in,
                              void* d_out, int out_size, void* d_ws, size_t ws_size,
                              hipStream_t stream) {
    const float* x = (const float*)d_in[0];
    float* out = (float*)d_out;
    bilinear_kernel<<<TOTAL_BLOCKS, BLOCK, 0, stream>>>(x, out);
}

// Round 5
// 248.715 us; speedup vs baseline: 1.0638x; 1.0208x over previous
//
#include <hip/hip_runtime.h>
#include <stdint.h>

// Bilinear sampling: x is (B=128, H=224, W=224, 5) f32 interleaved
// [r,g,b,X,Y]; out is (B,224,224,3) f32.
//
// R7: force 16-deep gather MLP with inline asm. R4b/R5/R6 all compiled to
// VGPR=40-44 -> the compiler serialized the gather batch into a ~4-deep
// window every time; the latency-hiding theory was never actually tested.
// This version:
//  - 16 volatile inline-asm global_load_dwordx4, issued back-to-back;
//  - ONE inline-asm "s_waitcnt vmcnt(0)" carrying all 16 results as "+v"
//    operands: forces 64 result VGPRs live (no re-rolling possible) and
//    makes every consumer data-dependent on the post-wait values (safe
//    ordering without sched_barrier tricks).
//  - right-corner loads folded via offset:16 (ROW_BYTES=4480 exceeds the
//    13-bit signed inst offset, so each pixel carries 2 row bases).
// Kept: 4 consecutive pixels/thread (5 coalesced dwordx4 input loads),
// XCD swizzle, NT output stores.
// Inputs guarantee X,Y in [0,223) so the reference's pad/clip never fires.

#define HH 224
#define WW 224
#define NB 128

constexpr int PIX_PER_IMG    = HH * WW;                      // 50176
constexpr int BLOCK          = 256;
constexpr int P              = 4;                            // consecutive pixels/thread
constexpr int PIX_PER_BLOCK  = BLOCK * P;                    // 1024
constexpr int BLOCKS_PER_IMG = PIX_PER_IMG / PIX_PER_BLOCK;  // 49 (exact)
constexpr int TOTAL_BLOCKS   = NB * BLOCKS_PER_IMG;          // 6272
constexpr int ROW_BYTES      = WW * 5 * 4;                   // 4480

typedef float f32x4 __attribute__((ext_vector_type(4)));

__device__ __forceinline__ float4 ld4(const float* p) {
    return *reinterpret_cast<const float4*>(p);
}

__global__ __launch_bounds__(BLOCK) void bilinear_kernel(
    const float* __restrict__ x, float* __restrict__ out)
{
    // XCD-aware swizzle: all blocks of image b land on XCD (b & 7).
    int i    = blockIdx.x;
    int xcd  = i & 7;
    int slot = i >> 3;
    int b    = xcd + 8 * (slot / BLOCKS_PER_IMG);
    int tile = slot % BLOCKS_PER_IMG;
    int pix0 = tile * PIX_PER_BLOCK + (int)threadIdx.x * P;

    const float* img = x + (size_t)b * (PIX_PER_IMG * 5);
    const float* xp  = img + (size_t)pix0 * 5;

    // This thread's 4 pixels = 20 contiguous floats [r,g,b,X,Y]x4,
    // 80B-aligned -> 5 coalesced dwordx4 loads.
    float4 v0 = ld4(xp +  0);
    float4 v1 = ld4(xp +  4);
    float4 v2 = ld4(xp +  8);
    float4 v3 = ld4(xp + 12);
    float4 v4 = ld4(xp + 16);

    // pixel k: X at float 5k+3, Y at float 5k+4
    float X0 = v0.w, X1 = v2.x, X2 = v3.y, X3 = v4.z;
    float Y0 = v1.x, Y1 = v2.y, Y2 = v3.z, Y3 = v4.w;

    const char* base = reinterpret_cast<const char*>(img);

    // --- addresses + weights, all before any gather ---
#define PREP(k)                                                              \
    float fx##k = floorf(X##k);                                              \
    float fy##k = floorf(Y##k);                                              \
    float wx##k = X##k - fx##k;                                              \
    float wy##k = Y##k - fy##k;                                              \
    /* byte offset = (fyi*224 + fxi)*20; exact in fp32 (ints < 2^24) */      \
    uint64_t qa##k = (uint64_t)(base + (int)fmaf(fy##k, (float)ROW_BYTES,    \
                                                 fx##k * 20.0f));            \
    uint64_t qb##k = qa##k + (uint64_t)ROW_BYTES;

    PREP(0) PREP(1) PREP(2) PREP(3)

    // --- 16 gathers, issued back-to-back, results pinned in VGPRs ---
    f32x4 a0_0, b0_0, a1_0, b1_0;
    f32x4 a0_1, b0_1, a1_1, b1_1;
    f32x4 a0_2, b0_2, a1_2, b1_2;
    f32x4 a0_3, b0_3, a1_3, b1_3;

#define GATHER(k)                                                            \
    asm volatile("global_load_dwordx4 %0, %1, off"                           \
                 : "=v"(a0_##k) : "v"(qa##k));                               \
    asm volatile("global_load_dwordx4 %0, %1, off offset:16"                 \
                 : "=v"(b0_##k) : "v"(qa##k));                               \
    asm volatile("global_load_dwordx4 %0, %1, off"                           \
                 : "=v"(a1_##k) : "v"(qb##k));                               \
    asm volatile("global_load_dwordx4 %0, %1, off offset:16"                 \
                 : "=v"(b1_##k) : "v"(qb##k));

    GATHER(0) GATHER(1) GATHER(2) GATHER(3)

    // Single drain. All 16 results are "+v" operands: regalloc must keep
    // them simultaneously live, and consumers depend on the post-wait
    // values (correct ordering by dataflow alone).
    asm volatile("s_waitcnt vmcnt(0)"
                 : "+v"(a0_0), "+v"(b0_0), "+v"(a1_0), "+v"(b1_0),
                   "+v"(a0_1), "+v"(b0_1), "+v"(a1_1), "+v"(b1_1),
                   "+v"(a0_2), "+v"(b0_2), "+v"(a1_2), "+v"(b1_2),
                   "+v"(a0_3), "+v"(b0_3), "+v"(a1_3), "+v"(b1_3));

    float o[3 * P];
#define COMBINE(k)                                                           \
    {                                                                        \
        float w_tl = (1.f - wx##k) * (1.f - wy##k);                          \
        float w_tr = wx##k * (1.f - wy##k);                                  \
        float w_bl = (1.f - wx##k) * wy##k;                                  \
        float w_br = wx##k * wy##k;                                          \
        o[3*k+0] = w_tl*a0_##k.x + w_tr*b0_##k.y + w_bl*a1_##k.x + w_br*b1_##k.y; \
        o[3*k+1] = w_tl*a0_##k.y + w_tr*b0_##k.z + w_bl*a1_##k.y + w_br*b1_##k.z; \
        o[3*k+2] = w_tl*a0_##k.z + w_tr*b0_##k.w + w_bl*a1_##k.z + w_br*b1_##k.w; \
    }

    COMBINE(0) COMBINE(1) COMBINE(2) COMBINE(3)

    // 4 pixels * 12B = 48B contiguous, 48B-aligned -> 3 NT dwordx4 stores.
    float* op = out + ((size_t)b * PIX_PER_IMG + pix0) * 3;
    f32x4* ov = reinterpret_cast<f32x4*>(op);
    f32x4 s0 = { o[0], o[1], o[2],  o[3]  };
    f32x4 s1 = { o[4], o[5], o[6],  o[7]  };
    f32x4 s2 = { o[8], o[9], o[10], o[11] };
    __builtin_nontemporal_store(s0, ov + 0);
    __builtin_nontemporal_store(s1, ov + 1);
    __builtin_nontemporal_store(s2, ov + 2);
}

extern "C" void kernel_launch(void* const* d_in, const int* in_sizes, int n_in,
                              void* d_out, int out_size, void* d_ws, size_t ws_size,
                              hipStream_t stream) {
    const float* x = (const float*)d_in[0];
    float* out = (float*)d_out;
    bilinear_kernel<<<TOTAL_BLOCKS, BLOCK, 0, stream>>>(x, out);
}